// Round 4
// baseline (863.676 us; speedup 1.0000x reference)
//
#include <hip/hip_runtime.h>
#include <math.h>

// Min-sum BP LDPC decoder, LDS-resident messages in VAR-ORDER layout.
// msg[4v..4v+3] = var v's 4 edge messages -> var phase & epilogue are aligned
// b128 LDS ops (conflict-free). Check phase addresses its edges via positions
// cached in REGISTERS (packed 2x16b, 7 ints per check, d<=14), loaded once
// from posbs[] (positions renumbered contiguously in degree-sorted check
// order). Zero global loads inside the 10-iteration loop.
//
// R3 changes vs R2 (which regressed: per-iter global posbe reads = L2 latency):
//  - posbs in sorted-contiguous order; positions register-cached across iters
//  - threads own 4 CONSECUTIVE degree-sorted checks -> wave-uniform d
//  - __launch_bounds__(1024,4): VGPR cap 64 -> 128 (LDS caps 1 block/CU anyway)
//    so compiler can batch-issue loads (latency was the R2 bottleneck)
//  - var phase batch-issues all 8 b128 reads before computing

#define BLOCK 1024
#define NV    8192          // N variables
#define MC    4096          // M checks
#define NE    32768         // E edges (N * DV, DV=4)
#define VPT   (NV / BLOCK)  // 8 vars per thread
#define CPT   (MC / BLOCK)  // 4 checks per thread (consecutive sorted)
#define NITER 10
#define ALPHA 0.8f
#define CLAMP 20.0f
#define DCAP  14            // register-cache degree cap (7 packed ints/check)

// ws layout (ints), offsets multiple of 64 for alignment:
#define WS_POSW  0                       // [NE]   word pos of edge e (orig id)
#define WS_ST2   (NE)                    // [MC+1] edge prefix, sorted order
#define WS_SC    (NE + MC + 64)          // [MC]   orig check idx per sorted slot
#define WS_POSBS (NE + 2*MC + 128)       // [NE]   positions, sorted-contiguous
#define WS_PAD   (2*NE + 2*MC + 128)     // [1]    word pos of edge 0
// total ~ 2*NE + 2*MC + 192 ints ~= 295 KB of d_ws

// ---------------- setup: sort checks by degree, build posbs ----------------
__global__ __launch_bounds__(BLOCK)
void setup_all(const float* __restrict__ check_mask,
               const int*   __restrict__ check_adj,
               const int*   __restrict__ var_adj,
               int max_dc, int* __restrict__ ws)
{
    __shared__ int ldeg[MC], lcst[MC], lso[MC];   // 48 KB
    __shared__ int part[BLOCK];
    __shared__ int hist[64], hbase[64];
    const int t = threadIdx.x;
    if (t < 64) hist[t] = 0;

    // posw: var v's j-th edge (ascending edge id = var_adj row order) lives at
    // var-order word 4v+j. Slot order preserves the reference's f32 sum order.
#pragma unroll
    for (int k = 0; k < VPT; ++k) {
        const int v = t + k * BLOCK;
        const int4 a = ((const int4*)var_adj)[v];
        ws[WS_POSW + a.x] = 4 * v + 0;
        ws[WS_POSW + a.y] = 4 * v + 1;
        ws[WS_POSW + a.z] = 4 * v + 2;
        ws[WS_POSW + a.w] = 4 * v + 3;
    }
    __syncthreads();
#pragma unroll
    for (int k = 0; k < CPT; ++k) {
        const int c = t + k * BLOCK;
        int d = 0;
        for (int j = 0; j < max_dc; ++j)
            d += (check_mask[(size_t)c * max_dc + j] != 0.0f) ? 1 : 0;
        ldeg[c] = d;
        lcst[c] = check_adj[(size_t)c * max_dc];  // row start (edges check-sorted)
        atomicAdd(&hist[d & 63], 1);
    }
    __syncthreads();
    if (t == 0) { int s = 0; for (int i = 0; i < 64; ++i) { hbase[i] = s; s += hist[i]; } }
    __syncthreads();
#pragma unroll
    for (int k = 0; k < CPT; ++k) {
        const int c = t + k * BLOCK;
        const int pos = atomicAdd(&hbase[ldeg[c] & 63], 1);
        lso[pos] = c;
    }
    __syncthreads();

    // prefix-sum sorted degrees (4 consecutive per thread + block scan)
    int sd[CPT]; int mysum = 0;
#pragma unroll
    for (int k = 0; k < CPT; ++k) { sd[k] = ldeg[lso[CPT * t + k]]; mysum += sd[k]; }
    part[t] = mysum; __syncthreads();
    for (int ofs = 1; ofs < BLOCK; ofs <<= 1) {
        const int v = (t >= ofs) ? part[t - ofs] : 0; __syncthreads();
        part[t] += v; __syncthreads();
    }
    int run = part[t] - mysum;   // exclusive prefix

#pragma unroll
    for (int k = 0; k < CPT; ++k) {
        const int i = CPT * t + k;
        const int c = lso[i];
        ws[WS_ST2 + i] = run;
        ws[WS_SC + i]  = c;
        const int cst = lcst[c];
        for (int j = 0; j < sd[k]; ++j)
            ws[WS_POSBS + run + j] = ws[WS_POSW + cst + j];
        run += sd[k];
    }
    if (t == BLOCK - 1) ws[WS_ST2 + MC] = run;
    if (t == 0)         ws[WS_PAD] = ws[WS_POSW + 0];
}

// Register-cached check update: positions packed 2x16b in pkc[7] (static idx).
template<int DMAX>
__device__ __forceinline__ void check_reg(float* __restrict__ msg,
                                          const int* pkc, int d,
                                          unsigned sb31, float pad)
{
    int p[DMAX]; float x[DMAX];
#pragma unroll
    for (int j = 0; j < DMAX; ++j)
        p[j] = (pkc[j >> 1] >> ((j & 1) * 16)) & 0xffff;
#pragma unroll
    for (int j = 0; j < DMAX; ++j) { if (j >= d) break; x[j] = msg[p[j]]; }

    float min1 = pad, min2 = pad;
    unsigned par = 0;
#pragma unroll
    for (int j = 0; j < DMAX; ++j) {
        if (j >= d) break;
        par ^= __float_as_uint(x[j]);               // MSB = sign parity
        const float a = fabsf(x[j]);
        min2 = fminf(min2, fmaxf(min1, a));         // two smallest, dup-exact
        min1 = fminf(min1, a);
    }
    const unsigned tb = sb31 ^ (par & 0x80000000u);
#pragma unroll
    for (int j = 0; j < DMAX; ++j) {
        if (j >= d) break;
        const float a = fabsf(x[j]);
        const float m = (fabsf(a - min1) < 1e-9f) ? min2 : min1;  // ref tolerance
        const unsigned sm = tb ^ (__float_as_uint(x[j]) & 0x80000000u);
        msg[p[j]] = __uint_as_float(__float_as_uint(ALPHA * m) ^ sm);
    }
}

// Fallback for d > DCAP (rare, ~1 wave/block): batched global posbs reads.
__device__ __forceinline__ void check_glb(float* __restrict__ msg,
                                          const int* __restrict__ pp, int d,
                                          unsigned sb31, float pad)
{
    float min1 = pad, min2 = pad;
    unsigned par = 0;
    for (int j = 0; j < d; ++j) {
        const float xx = msg[pp[j]];
        par ^= __float_as_uint(xx);
        const float a = fabsf(xx);
        min2 = fminf(min2, fmaxf(min1, a));
        min1 = fminf(min1, a);
    }
    const unsigned tb = sb31 ^ (par & 0x80000000u);
    for (int j = 0; j < d; ++j) {
        const int   p  = pp[j];
        const float xx = msg[p];
        const float a  = fabsf(xx);
        const float m  = (fabsf(a - min1) < 1e-9f) ? min2 : min1;
        const unsigned sm = tb ^ (__float_as_uint(xx) & 0x80000000u);
        msg[p] = __uint_as_float(__float_as_uint(ALPHA * m) ^ sm);
    }
}

__global__ __launch_bounds__(BLOCK, 4)   // allow 128 VGPR; LDS caps 1 block/CU
void bp_decode(const float* __restrict__ syndrome,    // (B, M)
               const float* __restrict__ llr_g,       // (B, N)
               const int*   __restrict__ ws,
               float* __restrict__ out,               // marginals | hard | converged
               int B)
{
    __shared__ float msg[NE];   // 128 KB, var-order; ctv <-> vtc in place
    __shared__ float sh_pad;
    __shared__ int   mism;

    const int b = blockIdx.x;
    const int t = threadIdx.x;

#pragma unroll
    for (int k = 0; k < VPT; ++k)                     // ctv0 = 0
        ((float4*)msg)[t + k * BLOCK] = make_float4(0.f, 0.f, 0.f, 0.f);

    float llr[VPT];
#pragma unroll
    for (int k = 0; k < VPT; ++k)
        llr[k] = llr_g[(size_t)b * NV + t + k * BLOCK];

    const int pos0 = ws[WS_PAD];         // edge 0's word position
    const int v0   = pos0 >> 2;
    const int s0   = pos0 & 3;

    // my 4 consecutive degree-sorted checks
    const int4 s2a = *(const int4*)(ws + WS_ST2 + CPT * t);
    const int  s2e = ws[WS_ST2 + CPT * t + CPT];
    int s2[CPT + 1] = { s2a.x, s2a.y, s2a.z, s2a.w, s2e };
    int deg[CPT]; int dmax = 0;
#pragma unroll
    for (int k = 0; k < CPT; ++k) { deg[k] = s2[k + 1] - s2[k]; dmax = max(dmax, deg[k]); }
    unsigned sb31[CPT];
#pragma unroll
    for (int k = 0; k < CPT; ++k) {
        const int c = ws[WS_SC + CPT * t + k];
        sb31[k] = (syndrome[(size_t)b * MC + c] > 0.5f) ? 0x80000000u : 0u;
    }
    const int* __restrict__ posbs = ws + WS_POSBS;
    const bool cached = (dmax <= DCAP);

    int pk[CPT * 7];
#pragma unroll
    for (int k = 0; k < CPT; ++k) {
        const int base = s2[k];
        const int d    = cached ? deg[k] : 0;
#pragma unroll
        for (int jj = 0; jj < 7; ++jj) {
            const int j0 = 2 * jj, j1 = 2 * jj + 1;
            const int lo = (j0 < d) ? posbs[base + j0] : 0;
            const int hi = (j1 < d) ? posbs[base + j1] : 0;
            pk[k * 7 + jj] = lo | (hi << 16);
        }
    }
    __syncthreads();

    for (int it = 0; it < NITER; ++it) {
        // ---- variable phase: batch-issue 8 b128 reads, compute, store ----
        float4 f[VPT];
#pragma unroll
        for (int k = 0; k < VPT; ++k) f[k] = ((const float4*)msg)[t + k * BLOCK];
#pragma unroll
        for (int k = 0; k < VPT; ++k) {
            const int v = t + k * BLOCK;
            const float tot  = ((f[k].x + f[k].y) + f[k].z) + f[k].w;  // ref order
            const float base = llr[k] + tot;
            float4 o;
            o.x = fminf(fmaxf(base - f[k].x, -CLAMP), CLAMP);
            o.y = fminf(fmaxf(base - f[k].y, -CLAMP), CLAMP);
            o.z = fminf(fmaxf(base - f[k].z, -CLAMP), CLAMP);
            o.w = fminf(fmaxf(base - f[k].w, -CLAMP), CLAMP);
            if (v == v0) {   // reference's pad = |vtc[edge0]| + 1e6
                float vt = o.x;
                if (s0 == 1) vt = o.y; else if (s0 == 2) vt = o.z; else if (s0 == 3) vt = o.w;
                sh_pad = fabsf(vt) + 1.0e6f;
            }
            ((float4*)msg)[v] = o;
        }
        __syncthreads();
        const float pad = sh_pad;

        // ---- check phase: register-cached positions, scattered b32 ----
        if (cached) {
#pragma unroll
            for (int k = 0; k < CPT; ++k) {
                if (deg[k] <= 8) check_reg<8>(msg, pk + k * 7, deg[k], sb31[k], pad);
                else             check_reg<DCAP>(msg, pk + k * 7, deg[k], sb31[k], pad);
            }
        } else {
#pragma unroll
            for (int k = 0; k < CPT; ++k)
                check_glb(msg, posbs + s2[k], deg[k], sb31[k], pad);
        }
        __syncthreads();
    }

    // ---- finale: marginals, hard decisions, convergence ----
    float marg[VPT], hard[VPT];
    {
        float4 f[VPT];
#pragma unroll
        for (int k = 0; k < VPT; ++k) f[k] = ((const float4*)msg)[t + k * BLOCK];
#pragma unroll
        for (int k = 0; k < VPT; ++k) {
            const float tot = ((f[k].x + f[k].y) + f[k].z) + f[k].w;
            const float tl  = llr[k] + tot;
            const float mg  = 1.0f / (1.0f + expf(tl));   // sigmoid(-tl)
            marg[k] = mg;
            hard[k] = (mg > 0.5f) ? 1.0f : 0.0f;
        }
    }
    if (t == 0) mism = 0;
    __syncthreads();   // all ctv reads done; mism initialized

    const size_t BN = (size_t)B * NV;
#pragma unroll
    for (int k = 0; k < VPT; ++k) {
        const int v = t + k * BLOCK;
        out[(size_t)b * NV + v]      = marg[k];        // output 0: marginals
        out[BN + (size_t)b * NV + v] = hard[k];        // output 1: hard_decision
        const float h = hard[k];
        ((float4*)msg)[v] = make_float4(h, h, h, h);   // hard bit to all slots
    }
    __syncthreads();

    // syn_hat parity per check; converged iff == syndrome for all checks
#pragma unroll
    for (int k = 0; k < CPT; ++k) {
        int par = 0;
        if (cached) {
            const int* pkc = pk + k * 7;
            for (int j = 0; j < deg[k]; ++j) {
                const int p = (pkc[j >> 1] >> ((j & 1) * 16)) & 0xffff;
                par ^= (msg[p] != 0.0f) ? 1 : 0;
            }
        } else {
            const int* pp = posbs + s2[k];
            for (int j = 0; j < deg[k]; ++j)
                par ^= (msg[pp[j]] != 0.0f) ? 1 : 0;
        }
        if ((par != 0) != (sb31[k] != 0u)) mism = 1;   // benign race
    }
    __syncthreads();
    if (t == 0) out[2 * BN + b] = mism ? 0.0f : 1.0f;  // output 2: converged
}

extern "C" void kernel_launch(void* const* d_in, const int* in_sizes, int n_in,
                              void* d_out, int out_size, void* d_ws, size_t ws_size,
                              hipStream_t stream) {
    const float* syndrome   = (const float*)d_in[0];
    const float* llr        = (const float*)d_in[1];
    const int*   var_adj    = (const int*)d_in[2];
    // d_in[3] var_adj_mask: all ones (DV=4 exact) — unused
    const int*   check_adj  = (const int*)d_in[4];
    const float* check_mask = (const float*)d_in[5];
    // d_in[6] var_idx — implicit in posw; unused
    // d_in[7] pcm_dense — unused
    float* out = (float*)d_out;
    int*   ws  = (int*)d_ws;    // needs ~295 KB

    const int B      = in_sizes[0] / MC;      // 256
    const int max_dc = in_sizes[4] / MC;

    setup_all<<<1, BLOCK, 0, stream>>>(check_mask, check_adj, var_adj, max_dc, ws);
    bp_decode<<<B, BLOCK, 0, stream>>>(syndrome, llr, ws, out, B);
}

// Round 5
// 691.107 us; speedup vs baseline: 1.2497x; 1.2497x over previous
//
#include <hip/hip_runtime.h>
#include <math.h>

// Min-sum BP LDPC decoder, LDS-resident messages in VAR-ORDER layout.
// msg[4v..4v+3] = var v's 4 edge messages -> var phase & epilogue are aligned
// b128 LDS ops (conflict-free). Check phase addresses its edges via positions
// cached in REGISTERS (packed 2x16b, 7 ints per check, d<=14), loaded once
// from posbs[] (positions renumbered contiguously in degree-sorted check
// order). Zero global loads inside the 10-iteration loop.
//
// R4 fix vs R3 (which spilled: 450 MB scratch traffic, 598 us):
//  - the epilogue parity loop had a RUNTIME bound -> dynamic index into pk[]
//    -> whole pk array lowered to scratch -> every check-phase access hit
//    scratch for all 10 iters. Now unrolled with static DCAP bound + break;
//    every pk index is compile-time static.
//  - var phase batches b128 loads in two halves of 4 (peak live regs 32->16).

#define BLOCK 1024
#define NV    8192          // N variables
#define MC    4096          // M checks
#define NE    32768         // E edges (N * DV, DV=4)
#define VPT   (NV / BLOCK)  // 8 vars per thread
#define CPT   (MC / BLOCK)  // 4 checks per thread (consecutive sorted)
#define NITER 10
#define ALPHA 0.8f
#define CLAMP 20.0f
#define DCAP  14            // register-cache degree cap (7 packed ints/check)

// ws layout (ints), offsets multiple of 64 for alignment:
#define WS_POSW  0                       // [NE]   word pos of edge e (orig id)
#define WS_ST2   (NE)                    // [MC+1] edge prefix, sorted order
#define WS_SC    (NE + MC + 64)          // [MC]   orig check idx per sorted slot
#define WS_POSBS (NE + 2*MC + 128)       // [NE]   positions, sorted-contiguous
#define WS_PAD   (2*NE + 2*MC + 128)     // [1]    word pos of edge 0

// ---------------- setup: sort checks by degree, build posbs ----------------
__global__ __launch_bounds__(BLOCK)
void setup_all(const float* __restrict__ check_mask,
               const int*   __restrict__ check_adj,
               const int*   __restrict__ var_adj,
               int max_dc, int* __restrict__ ws)
{
    __shared__ int ldeg[MC], lcst[MC], lso[MC];   // 48 KB
    __shared__ int part[BLOCK];
    __shared__ int hist[64], hbase[64];
    const int t = threadIdx.x;
    if (t < 64) hist[t] = 0;

    // posw: var v's j-th edge (ascending edge id = var_adj row order) lives at
    // var-order word 4v+j. Slot order preserves the reference's f32 sum order.
#pragma unroll
    for (int k = 0; k < VPT; ++k) {
        const int v = t + k * BLOCK;
        const int4 a = ((const int4*)var_adj)[v];
        ws[WS_POSW + a.x] = 4 * v + 0;
        ws[WS_POSW + a.y] = 4 * v + 1;
        ws[WS_POSW + a.z] = 4 * v + 2;
        ws[WS_POSW + a.w] = 4 * v + 3;
    }
    __syncthreads();
#pragma unroll
    for (int k = 0; k < CPT; ++k) {
        const int c = t + k * BLOCK;
        int d = 0;
        for (int j = 0; j < max_dc; ++j)
            d += (check_mask[(size_t)c * max_dc + j] != 0.0f) ? 1 : 0;
        ldeg[c] = d;
        lcst[c] = check_adj[(size_t)c * max_dc];  // row start (edges check-sorted)
        atomicAdd(&hist[d & 63], 1);
    }
    __syncthreads();
    if (t == 0) { int s = 0; for (int i = 0; i < 64; ++i) { hbase[i] = s; s += hist[i]; } }
    __syncthreads();
#pragma unroll
    for (int k = 0; k < CPT; ++k) {
        const int c = t + k * BLOCK;
        const int pos = atomicAdd(&hbase[ldeg[c] & 63], 1);
        lso[pos] = c;
    }
    __syncthreads();

    // prefix-sum sorted degrees (4 consecutive per thread + block scan)
    int sd[CPT]; int mysum = 0;
#pragma unroll
    for (int k = 0; k < CPT; ++k) { sd[k] = ldeg[lso[CPT * t + k]]; mysum += sd[k]; }
    part[t] = mysum; __syncthreads();
    for (int ofs = 1; ofs < BLOCK; ofs <<= 1) {
        const int v = (t >= ofs) ? part[t - ofs] : 0; __syncthreads();
        part[t] += v; __syncthreads();
    }
    int run = part[t] - mysum;   // exclusive prefix

#pragma unroll
    for (int k = 0; k < CPT; ++k) {
        const int i = CPT * t + k;
        const int c = lso[i];
        ws[WS_ST2 + i] = run;
        ws[WS_SC + i]  = c;
        const int cst = lcst[c];
        for (int j = 0; j < sd[k]; ++j)
            ws[WS_POSBS + run + j] = ws[WS_POSW + cst + j];
        run += sd[k];
    }
    if (t == BLOCK - 1) ws[WS_ST2 + MC] = run;
    if (t == 0)         ws[WS_PAD] = ws[WS_POSW + 0];
}

// Register-cached check update: positions packed 2x16b in pkc[7].
// ALL pk indices are compile-time static (j>>1 with j from unrolled loop).
template<int DMAX>
__device__ __forceinline__ void check_reg(float* __restrict__ msg,
                                          const int* pkc, int d,
                                          unsigned sb31, float pad)
{
    int p[DMAX]; float x[DMAX];
#pragma unroll
    for (int j = 0; j < DMAX; ++j)
        p[j] = (pkc[j >> 1] >> ((j & 1) * 16)) & 0xffff;
#pragma unroll
    for (int j = 0; j < DMAX; ++j) { if (j >= d) break; x[j] = msg[p[j]]; }

    float min1 = pad, min2 = pad;
    unsigned par = 0;
#pragma unroll
    for (int j = 0; j < DMAX; ++j) {
        if (j >= d) break;
        par ^= __float_as_uint(x[j]);               // MSB = sign parity
        const float a = fabsf(x[j]);
        min2 = fminf(min2, fmaxf(min1, a));         // two smallest, dup-exact
        min1 = fminf(min1, a);
    }
    const unsigned tb = sb31 ^ (par & 0x80000000u);
#pragma unroll
    for (int j = 0; j < DMAX; ++j) {
        if (j >= d) break;
        const float a = fabsf(x[j]);
        const float m = (fabsf(a - min1) < 1e-9f) ? min2 : min1;  // ref tolerance
        const unsigned sm = tb ^ (__float_as_uint(x[j]) & 0x80000000u);
        msg[p[j]] = __uint_as_float(__float_as_uint(ALPHA * m) ^ sm);
    }
}

// Fallback for d > DCAP (rare, ~1.7% of checks): batched global posbs reads.
__device__ __forceinline__ void check_glb(float* __restrict__ msg,
                                          const int* __restrict__ pp, int d,
                                          unsigned sb31, float pad)
{
    float min1 = pad, min2 = pad;
    unsigned par = 0;
    for (int j = 0; j < d; ++j) {
        const float xx = msg[pp[j]];
        par ^= __float_as_uint(xx);
        const float a = fabsf(xx);
        min2 = fminf(min2, fmaxf(min1, a));
        min1 = fminf(min1, a);
    }
    const unsigned tb = sb31 ^ (par & 0x80000000u);
    for (int j = 0; j < d; ++j) {
        const int   p  = pp[j];
        const float xx = msg[p];
        const float a  = fabsf(xx);
        const float m  = (fabsf(a - min1) < 1e-9f) ? min2 : min1;
        const unsigned sm = tb ^ (__float_as_uint(xx) & 0x80000000u);
        msg[p] = __uint_as_float(__float_as_uint(ALPHA * m) ^ sm);
    }
}

__global__ __launch_bounds__(BLOCK, 4)   // 4 waves/EU -> 128 VGPR cap; LDS caps 1 block/CU
void bp_decode(const float* __restrict__ syndrome,    // (B, M)
               const float* __restrict__ llr_g,       // (B, N)
               const int*   __restrict__ ws,
               float* __restrict__ out,               // marginals | hard | converged
               int B)
{
    __shared__ float msg[NE];   // 128 KB, var-order; ctv <-> vtc in place
    __shared__ float sh_pad;
    __shared__ int   mism;

    const int b = blockIdx.x;
    const int t = threadIdx.x;

#pragma unroll
    for (int k = 0; k < VPT; ++k)                     // ctv0 = 0
        ((float4*)msg)[t + k * BLOCK] = make_float4(0.f, 0.f, 0.f, 0.f);

    float llr[VPT];
#pragma unroll
    for (int k = 0; k < VPT; ++k)
        llr[k] = llr_g[(size_t)b * NV + t + k * BLOCK];

    const int pos0 = ws[WS_PAD];         // edge 0's word position
    const int v0   = pos0 >> 2;
    const int s0   = pos0 & 3;

    // my 4 consecutive degree-sorted checks
    const int4 s2a = *(const int4*)(ws + WS_ST2 + CPT * t);
    const int  s2e = ws[WS_ST2 + CPT * t + CPT];
    int s2[CPT + 1] = { s2a.x, s2a.y, s2a.z, s2a.w, s2e };
    int deg[CPT]; int dmax = 0;
#pragma unroll
    for (int k = 0; k < CPT; ++k) { deg[k] = s2[k + 1] - s2[k]; dmax = max(dmax, deg[k]); }
    unsigned sb31[CPT];
#pragma unroll
    for (int k = 0; k < CPT; ++k) {
        const int c = ws[WS_SC + CPT * t + k];
        sb31[k] = (syndrome[(size_t)b * MC + c] > 0.5f) ? 0x80000000u : 0u;
    }
    const int* __restrict__ posbs = ws + WS_POSBS;
    const bool cached = (dmax <= DCAP);

    int pk[CPT * 7];
#pragma unroll
    for (int k = 0; k < CPT; ++k) {
        const int base = s2[k];
        const int d    = cached ? deg[k] : 0;
#pragma unroll
        for (int jj = 0; jj < 7; ++jj) {
            const int j0 = 2 * jj, j1 = 2 * jj + 1;
            const int lo = (j0 < d) ? posbs[base + j0] : 0;
            const int hi = (j1 < d) ? posbs[base + j1] : 0;
            pk[k * 7 + jj] = lo | (hi << 16);
        }
    }
    __syncthreads();

    for (int it = 0; it < NITER; ++it) {
        // ---- variable phase: two half-batches of 4 b128 reads ----
#pragma unroll
        for (int h = 0; h < 2; ++h) {
            float4 f[VPT / 2];
#pragma unroll
            for (int k = 0; k < VPT / 2; ++k)
                f[k] = ((const float4*)msg)[t + (h * (VPT / 2) + k) * BLOCK];
#pragma unroll
            for (int k = 0; k < VPT / 2; ++k) {
                const int kk = h * (VPT / 2) + k;
                const int v  = t + kk * BLOCK;
                const float tot  = ((f[k].x + f[k].y) + f[k].z) + f[k].w;  // ref order
                const float base = llr[kk] + tot;
                float4 o;
                o.x = fminf(fmaxf(base - f[k].x, -CLAMP), CLAMP);
                o.y = fminf(fmaxf(base - f[k].y, -CLAMP), CLAMP);
                o.z = fminf(fmaxf(base - f[k].z, -CLAMP), CLAMP);
                o.w = fminf(fmaxf(base - f[k].w, -CLAMP), CLAMP);
                if (v == v0) {   // reference's pad = |vtc[edge0]| + 1e6
                    float vt = o.x;
                    if (s0 == 1) vt = o.y; else if (s0 == 2) vt = o.z; else if (s0 == 3) vt = o.w;
                    sh_pad = fabsf(vt) + 1.0e6f;
                }
                ((float4*)msg)[v] = o;
            }
        }
        __syncthreads();
        const float pad = sh_pad;

        // ---- check phase: register-cached positions, scattered b32 ----
        if (cached) {
#pragma unroll
            for (int k = 0; k < CPT; ++k) {
                if (deg[k] <= 8) check_reg<8>(msg, pk + k * 7, deg[k], sb31[k], pad);
                else             check_reg<DCAP>(msg, pk + k * 7, deg[k], sb31[k], pad);
            }
        } else {
#pragma unroll
            for (int k = 0; k < CPT; ++k)
                check_glb(msg, posbs + s2[k], deg[k], sb31[k], pad);
        }
        __syncthreads();
    }

    // ---- finale: marginals, hard decisions, convergence ----
    float marg[VPT], hard[VPT];
#pragma unroll
    for (int h = 0; h < 2; ++h) {
        float4 f[VPT / 2];
#pragma unroll
        for (int k = 0; k < VPT / 2; ++k)
            f[k] = ((const float4*)msg)[t + (h * (VPT / 2) + k) * BLOCK];
#pragma unroll
        for (int k = 0; k < VPT / 2; ++k) {
            const int kk = h * (VPT / 2) + k;
            const float tot = ((f[k].x + f[k].y) + f[k].z) + f[k].w;
            const float tl  = llr[kk] + tot;
            const float mg  = 1.0f / (1.0f + expf(tl));   // sigmoid(-tl)
            marg[kk] = mg;
            hard[kk] = (mg > 0.5f) ? 1.0f : 0.0f;
        }
    }
    if (t == 0) mism = 0;
    __syncthreads();   // all ctv reads done; mism initialized

    const size_t BN = (size_t)B * NV;
#pragma unroll
    for (int k = 0; k < VPT; ++k) {
        const int v = t + k * BLOCK;
        out[(size_t)b * NV + v]      = marg[k];        // output 0: marginals
        out[BN + (size_t)b * NV + v] = hard[k];        // output 1: hard_decision
        const float h = hard[k];
        ((float4*)msg)[v] = make_float4(h, h, h, h);   // hard bit to all slots
    }
    __syncthreads();

    // syn_hat parity per check; UNROLLED with static bound so pk indexing
    // stays static (the R3 spill bug was a runtime-bound loop right here).
#pragma unroll
    for (int k = 0; k < CPT; ++k) {
        int par = 0;
        if (cached) {
            const int* pkc = pk + k * 7;
#pragma unroll
            for (int j = 0; j < DCAP; ++j) {
                if (j >= deg[k]) break;
                const int p = (pkc[j >> 1] >> ((j & 1) * 16)) & 0xffff;
                par ^= (msg[p] != 0.0f) ? 1 : 0;
            }
        } else {
            const int* pp = posbs + s2[k];
            for (int j = 0; j < deg[k]; ++j)
                par ^= (msg[pp[j]] != 0.0f) ? 1 : 0;
        }
        if ((par != 0) != (sb31[k] != 0u)) mism = 1;   // benign race
    }
    __syncthreads();
    if (t == 0) out[2 * BN + b] = mism ? 0.0f : 1.0f;  // output 2: converged
}

extern "C" void kernel_launch(void* const* d_in, const int* in_sizes, int n_in,
                              void* d_out, int out_size, void* d_ws, size_t ws_size,
                              hipStream_t stream) {
    const float* syndrome   = (const float*)d_in[0];
    const float* llr        = (const float*)d_in[1];
    const int*   var_adj    = (const int*)d_in[2];
    // d_in[3] var_adj_mask: all ones (DV=4 exact) — unused
    const int*   check_adj  = (const int*)d_in[4];
    const float* check_mask = (const float*)d_in[5];
    // d_in[6] var_idx — implicit in posw; unused
    // d_in[7] pcm_dense — unused
    float* out = (float*)d_out;
    int*   ws  = (int*)d_ws;    // needs ~295 KB

    const int B      = in_sizes[0] / MC;      // 256
    const int max_dc = in_sizes[4] / MC;

    setup_all<<<1, BLOCK, 0, stream>>>(check_mask, check_adj, var_adj, max_dc, ws);
    bp_decode<<<B, BLOCK, 0, stream>>>(syndrome, llr, ws, out, B);
}